// Round 5
// baseline (198.313 us; speedup 1.0000x reference)
//
#include <hip/hip_runtime.h>
#include <stdint.h>

typedef _Float16 f16;
typedef _Float16 f16x2 __attribute__((ext_vector_type(2)));
typedef _Float16 f16x4 __attribute__((ext_vector_type(4)));
typedef _Float16 f16x8 __attribute__((ext_vector_type(8)));
typedef float f32x4 __attribute__((ext_vector_type(4)));

#define LOG2E 1.44269504088896340736f

__device__ __forceinline__ f32x4 mfma_16x16x32(f16x8 a, f16x8 b, f32x4 c) {
    return __builtin_amdgcn_mfma_f32_16x16x32_f16(a, b, c, 0, 0, 0);
}

__device__ __forceinline__ void gload_lds16(const void* g, void* l) {
    __builtin_amdgcn_global_load_lds(
        (const __attribute__((address_space(1))) unsigned int*)g,
        (__attribute__((address_space(3))) unsigned int*)l, 16, 0, 0);
}

__device__ __forceinline__ f16x2 cvt_pk_f16(float a, float b) {
    return __builtin_bit_cast(f16x2, __builtin_amdgcn_cvt_pkrtz(a, b));
}

// ---------------- cast f32 -> f16, 4 elements/thread ----------------
__global__ void cast_f32_f16(const float* __restrict__ src, f16* __restrict__ dst, int n4) {
    int i = blockIdx.x * 256 + threadIdx.x;
    if (i >= n4) return;
    float4 v = reinterpret_cast<const float4*>(src)[i];
    f16x4 o;
    o[0] = (f16)v.x; o[1] = (f16)v.y; o[2] = (f16)v.z; o[3] = (f16)v.w;
    reinterpret_cast<f16x4*>(dst)[i] = o;
}

// ---------------- TN GEMM: C[M][N] = A[M][K] * W[N][K]^T + bias ----------------
// MODE 0: scatter to Q/K/V f16 buffers [B=4][H=16][T=2048][D=64], Q scaled by 0.125*log2(e)
// MODE 1: f32 output [M][N] with bias
template<int MODE>
__global__ __launch_bounds__(256, 2)
void gemm_tn(const f16* __restrict__ A, const f16* __restrict__ W,
             const float* __restrict__ bias, void* __restrict__ outp,
             int M, int N, int K)
{
    __shared__ __align__(16) f16 As[128 * 32];
    __shared__ __align__(16) f16 Bs[128 * 32];

    const int lane = threadIdx.x & 63;
    const int wave = threadIdx.x >> 6;
    const int l15 = lane & 15, l4 = lane >> 4;

    // bijective XCD swizzle (T1)
    const int nwg = (int)(gridDim.x * gridDim.y);
    int orig = (int)(blockIdx.y * gridDim.x + blockIdx.x);
    int cpx = nwg >> 3;
    int w = (orig & 7) * cpx + (orig >> 3);
    const int row0 = (w / (int)gridDim.x) * 128;
    const int col0 = (w % (int)gridDim.x) * 128;
    const int wr = wave >> 1, wc = wave & 1;

    f32x4 acc[4][4] = {};

    const int srow = lane >> 2;
    const int scol = (lane & 3) * 8;

    for (int k0 = 0; k0 < K; k0 += 32) {
        __syncthreads();
        #pragma unroll
        for (int it = 0; it < 2; ++it) {
            int chunk = it * 4 + wave;
            const f16* gA = A + (size_t)(row0 + chunk * 16 + srow) * K + k0 + scol;
            gload_lds16(gA, As + chunk * 512);
            const f16* gB = W + (size_t)(col0 + chunk * 16 + srow) * K + k0 + scol;
            gload_lds16(gB, Bs + chunk * 512);
        }
        __syncthreads();

        f16x8 af[4], bf[4];
        #pragma unroll
        for (int m = 0; m < 4; ++m)
            af[m] = *reinterpret_cast<const f16x8*>(As + (wr * 64 + m * 16 + l15) * 32 + l4 * 8);
        #pragma unroll
        for (int n = 0; n < 4; ++n)
            bf[n] = *reinterpret_cast<const f16x8*>(Bs + (wc * 64 + n * 16 + l15) * 32 + l4 * 8);
        #pragma unroll
        for (int m = 0; m < 4; ++m)
            #pragma unroll
            for (int n = 0; n < 4; ++n)
                acc[m][n] = mfma_16x16x32(af[m], bf[n], acc[m][n]);
    }

    if (MODE == 0) {
        f16* qb = (f16*)outp;
        const size_t HS = (size_t)64 * 2048 * 64;
        #pragma unroll
        for (int m = 0; m < 4; ++m) {
            int rbase = row0 + wr * 64 + m * 16 + l4 * 4;
            #pragma unroll
            for (int n = 0; n < 4; ++n) {
                int j = col0 + wc * 64 + n * 16 + l15;
                int which = j >> 10;
                int h = (j >> 6) & 15;
                int d = j & 63;
                float bj = bias[j];
                f16* base = qb + (size_t)which * HS;
                float scale = (which == 0) ? (0.125f * LOG2E) : 1.0f;
                #pragma unroll
                for (int r = 0; r < 4; ++r) {
                    int row = rbase + r;
                    int b = row >> 11, t = row & 2047;
                    size_t off = ((size_t)(b * 16 + h) * 2048 + t) * 64 + d;
                    base[off] = (f16)((acc[m][n][r] + bj) * scale);
                }
            }
        }
    } else {
        float* O = (float*)outp;
        #pragma unroll
        for (int m = 0; m < 4; ++m) {
            int rbase = row0 + wr * 64 + m * 16 + l4 * 4;
            #pragma unroll
            for (int n = 0; n < 4; ++n) {
                int j = col0 + wc * 64 + n * 16 + l15;
                float bj = bias[j];
                #pragma unroll
                for (int r = 0; r < 4; ++r)
                    O[(size_t)(rbase + r) * N + j] = acc[m][n][r] + bj;
            }
        }
    }
}

// ---------------- flash attention: pipelined, double-buffered, defer-max ----------------
// grid: (bh=64, qblk=32 reversed), block 256 = 4 waves; wave owns 16 q-rows.
// Per tile: [scatter V_t from regs] -> barrier -> [issue K/V for t+1] -> [compute t].
// __syncthreads' implicit vmcnt(0) drain gives each load a full compute-phase of hiding.
__global__ __launch_bounds__(256, 3)
void attn_kernel(const f16* __restrict__ qb, const f16* __restrict__ kb,
                 const f16* __restrict__ vb, f16* __restrict__ ob)
{
    __shared__ __align__(16) f16 Ks[2][64 * 64];   // [buf][key][d], 16B-chunk XOR-swizzled
    __shared__ __align__(16) f16 Vs[2][64][72];    // [buf][d][key] transposed
    __shared__ __align__(16) f16 Ps[4][16][72];    // per-wave P tile [q][key]

    const int tid = (int)threadIdx.x;
    const int bh = (int)blockIdx.x;
    const int qblk = (int)gridDim.y - 1 - (int)blockIdx.y;  // longest first
    const int lane = tid & 63;
    const int wave = tid >> 6;
    const int l15 = lane & 15, l4 = lane >> 4;
    const int q0 = qblk * 64;
    const int qw = q0 + wave * 16;                 // wave's first q-row

    // Q B-frag (pre-scaled by 0.125*log2e): col=q=l15, k(d) = kc*32 + l4*8 + j
    const f16* Qp = qb + ((size_t)bh * 2048 + qw) * 64;
    f16x8 aq0 = *reinterpret_cast<const f16x8*>(Qp + l15 * 64 + l4 * 8);
    f16x8 aq1 = *reinterpret_cast<const f16x8*>(Qp + l15 * 64 + 32 + l4 * 8);

    float Mr = -1e30f, Lr = 0.0f;
    f32x4 oacc[4] = {};

    const int ntiles = q0 / 64 + 1;
    const f16* Kbh = kb + (size_t)bh * 2048 * 64;
    const f16* Vbh = vb + (size_t)bh * 2048 * 64;

    // ---- prologue: issue tile 0 loads ----
    f16x8 vld0, vld1;
    {
        #pragma unroll
        for (int it = 0; it < 2; ++it) {
            int c = it * 256 + tid;
            int krow = c >> 3;
            int s16 = (c & 7) ^ (krow & 7);
            gload_lds16(Kbh + krow * 64 + s16 * 8, &Ks[0][0] + it * 2048 + wave * 512);
        }
        vld0 = *reinterpret_cast<const f16x8*>(Vbh + lane * 64 + (wave * 2 + 0) * 8);
        vld1 = *reinterpret_cast<const f16x8*>(Vbh + lane * 64 + (wave * 2 + 1) * 8);
    }

    for (int t = 0; t < ntiles; ++t) {
        const int cur = t & 1;

        // A: scatter V_t regs -> Vs[cur] (vmcnt wait on vld* here; hidden by prior compute)
        #pragma unroll
        for (int it = 0; it < 2; ++it) {
            int dblk = wave * 2 + it;
            const f16x8 v = it ? vld1 : vld0;
            #pragma unroll
            for (int e = 0; e < 8; ++e)
                Vs[cur][dblk * 8 + e][lane] = v[e];
        }

        __syncthreads();   // drains K_t gload_lds; makes Vs[cur] visible; syncs buffers

        // B: issue tile t+1 loads into the other buffer (clamped on last iter)
        {
            const int kvn = (t + 1 < ntiles) ? (t + 1) * 64 : t * 64;
            const f16* Ktn = Kbh + (size_t)kvn * 64;
            #pragma unroll
            for (int it = 0; it < 2; ++it) {
                int c = it * 256 + tid;
                int krow = c >> 3;
                int s16 = (c & 7) ^ (krow & 7);
                gload_lds16(Ktn + krow * 64 + s16 * 8, &Ks[cur ^ 1][0] + it * 2048 + wave * 512);
            }
            const f16* Vtn = Vbh + (size_t)kvn * 64;
            vld0 = *reinterpret_cast<const f16x8*>(Vtn + lane * 64 + (wave * 2 + 0) * 8);
            vld1 = *reinterpret_cast<const f16x8*>(Vtn + lane * 64 + (wave * 2 + 1) * 8);
        }

        // D: compute tile t
        // S^T = K * Q^T: col = q = l15, row = key_local = n*16 + l4*4 + r
        f32x4 s[4];
        __builtin_amdgcn_s_setprio(1);
        #pragma unroll
        for (int n = 0; n < 4; ++n) {
            int key = n * 16 + l15;
            int cs = key & 7;
            f16x8 kf0 = *reinterpret_cast<const f16x8*>(&Ks[cur][0] + key * 64 + ((l4 ^ cs) * 8));
            f16x8 kf1 = *reinterpret_cast<const f16x8*>(&Ks[cur][0] + key * 64 + (((4 + l4) ^ cs) * 8));
            f32x4 c = {};
            c = mfma_16x16x32(kf0, aq0, c);
            c = mfma_16x16x32(kf1, aq1, c);
            s[n] = c;
        }
        __builtin_amdgcn_s_setprio(0);

        if (t == ntiles - 1) {             // diagonal tile: causal mask
            #pragma unroll
            for (int n = 0; n < 4; ++n)
                #pragma unroll
                for (int r = 0; r < 4; ++r)
                    if (n * 16 + l4 * 4 + r > wave * 16 + l15) s[n][r] = -1e30f;
        }

        // in-lane softmax for q-row l15 (log2 domain), defer-max (T13, THR=8)
        float mx = -1e30f;
        #pragma unroll
        for (int n = 0; n < 4; ++n)
            #pragma unroll
            for (int r = 0; r < 4; ++r)
                mx = fmaxf(mx, s[n][r]);
        mx = fmaxf(mx, __shfl_xor(mx, 16));
        mx = fmaxf(mx, __shfl_xor(mx, 32));

        if (__any(mx > Mr + 8.0f)) {
            float nm = fmaxf(Mr, mx);
            float alpha = exp2f(Mr - nm);
            Mr = nm;
            float ar[4];
            #pragma unroll
            for (int r = 0; r < 4; ++r) ar[r] = __shfl(alpha, l4 * 4 + r);
            #pragma unroll
            for (int dt = 0; dt < 4; ++dt) {
                oacc[dt][0] *= ar[0]; oacc[dt][1] *= ar[1];
                oacc[dt][2] *= ar[2]; oacc[dt][3] *= ar[3];
            }
            Lr *= alpha;
        }

        float rs = 0.0f;
        #pragma unroll
        for (int n = 0; n < 4; ++n) {
            float p0 = exp2f(s[n][0] - Mr);
            float p1 = exp2f(s[n][1] - Mr);
            float p2 = exp2f(s[n][2] - Mr);
            float p3 = exp2f(s[n][3] - Mr);
            rs += (p0 + p1) + (p2 + p3);
            f16x2 lo = cvt_pk_f16(p0, p1);
            f16x2 hi = cvt_pk_f16(p2, p3);
            f16x4 pk; pk[0] = lo[0]; pk[1] = lo[1]; pk[2] = hi[0]; pk[3] = hi[1];
            *reinterpret_cast<f16x4*>(&Ps[wave][l15][n * 16 + l4 * 4]) = pk;
        }
        rs += __shfl_xor(rs, 16);
        rs += __shfl_xor(rs, 32);
        Lr += rs;

        // PV: O += P[16x64] * V[64x64]  (same-wave LDS write->read)
        f16x8 pa0 = *reinterpret_cast<const f16x8*>(&Ps[wave][l15][l4 * 8]);
        f16x8 pa1 = *reinterpret_cast<const f16x8*>(&Ps[wave][l15][32 + l4 * 8]);
        __builtin_amdgcn_s_setprio(1);
        #pragma unroll
        for (int dt = 0; dt < 4; ++dt) {
            int d = dt * 16 + l15;
            f16x8 v0 = *reinterpret_cast<const f16x8*>(&Vs[cur][d][l4 * 8]);
            f16x8 v1 = *reinterpret_cast<const f16x8*>(&Vs[cur][d][32 + l4 * 8]);
            oacc[dt] = mfma_16x16x32(pa0, v0, oacc[dt]);
            oacc[dt] = mfma_16x16x32(pa1, v1, oacc[dt]);
        }
        __builtin_amdgcn_s_setprio(0);
    }

    // normalize + store to [B][T][H*64+d] f16
    float lr[4];
    #pragma unroll
    for (int r = 0; r < 4; ++r) lr[r] = __shfl(Lr, l4 * 4 + r);

    const int b = bh >> 4, h = bh & 15;
    f16* O = ob + ((size_t)b * 2048 + qw) * 1024 + h * 64;
    #pragma unroll
    for (int dt = 0; dt < 4; ++dt) {
        int d = dt * 16 + l15;
        #pragma unroll
        for (int r = 0; r < 4; ++r)
            O[(size_t)(l4 * 4 + r) * 1024 + d] = (f16)(oacc[dt][r] / lr[r]);
    }
}

extern "C" void kernel_launch(void* const* d_in, const int* in_sizes, int n_in,
                              void* d_out, int out_size, void* d_ws, size_t ws_size,
                              hipStream_t stream)
{
    const float* x    = (const float*)d_in[0];
    const float* qkvw = (const float*)d_in[1];
    const float* qkvb = (const float*)d_in[2];
    const float* outw = (const float*)d_in[3];
    const float* outb = (const float*)d_in[4];
    float* out = (float*)d_out;

    f16* x_h    = (f16*)d_ws;
    f16* qkvw_h = x_h + (size_t)8192 * 1024;
    f16* outw_h = qkvw_h + (size_t)3072 * 1024;
    f16* q_buf  = outw_h + (size_t)1024 * 1024;
    f16* att_o  = q_buf + (size_t)3 * 8388608;

    cast_f32_f16<<<8192, 256, 0, stream>>>(x, x_h, 2097152);
    cast_f32_f16<<<3072, 256, 0, stream>>>(qkvw, qkvw_h, 786432);
    cast_f32_f16<<<1024, 256, 0, stream>>>(outw, outw_h, 262144);

    gemm_tn<0><<<dim3(24, 64), 256, 0, stream>>>(x_h, qkvw_h, qkvb, q_buf, 8192, 3072, 1024);
    attn_kernel<<<dim3(64, 32), 256, 0, stream>>>(q_buf, q_buf + 8388608, q_buf + 2 * 8388608, att_o);
    gemm_tn<1><<<dim3(8, 64), 256, 0, stream>>>(att_o, outw_h, outb, out, 8192, 1024, 1024);
}

// Round 8
// 191.094 us; speedup vs baseline: 1.0378x; 1.0378x over previous
//
#include <hip/hip_runtime.h>
#include <stdint.h>

typedef _Float16 f16;
typedef _Float16 f16x2 __attribute__((ext_vector_type(2)));
typedef _Float16 f16x4 __attribute__((ext_vector_type(4)));
typedef _Float16 f16x8 __attribute__((ext_vector_type(8)));
typedef float f32x4 __attribute__((ext_vector_type(4)));
typedef float f32x16 __attribute__((ext_vector_type(16)));

#define LOG2E 1.44269504088896340736f

__device__ __forceinline__ f32x4 mfma_16x16x32(f16x8 a, f16x8 b, f32x4 c) {
    return __builtin_amdgcn_mfma_f32_16x16x32_f16(a, b, c, 0, 0, 0);
}
__device__ __forceinline__ f32x16 mfma_32x32x16(f16x8 a, f16x8 b, f32x16 c) {
    return __builtin_amdgcn_mfma_f32_32x32x16_f16(a, b, c, 0, 0, 0);
}

__device__ __forceinline__ void gload_lds16(const void* g, void* l) {
    __builtin_amdgcn_global_load_lds(
        (const __attribute__((address_space(1))) unsigned int*)g,
        (__attribute__((address_space(3))) unsigned int*)l, 16, 0, 0);
}

__device__ __forceinline__ f16x2 cvt_pk_f16(float a, float b) {
    return __builtin_bit_cast(f16x2, __builtin_amdgcn_cvt_pkrtz(a, b));
}

// ---------------- cast f32 -> f16, 4 elements/thread ----------------
__global__ void cast_f32_f16(const float* __restrict__ src, f16* __restrict__ dst, int n4) {
    int i = blockIdx.x * 256 + threadIdx.x;
    if (i >= n4) return;
    float4 v = reinterpret_cast<const float4*>(src)[i];
    f16x4 o;
    o[0] = (f16)v.x; o[1] = (f16)v.y; o[2] = (f16)v.z; o[3] = (f16)v.w;
    reinterpret_cast<f16x4*>(dst)[i] = o;
}

// ---------------- TN GEMM (unchanged, passing since R2) ----------------
template<int MODE>
__global__ __launch_bounds__(256, 2)
void gemm_tn(const f16* __restrict__ A, const f16* __restrict__ W,
             const float* __restrict__ bias, void* __restrict__ outp,
             int M, int N, int K)
{
    __shared__ __align__(16) f16 As[128 * 32];
    __shared__ __align__(16) f16 Bs[128 * 32];

    const int lane = threadIdx.x & 63;
    const int wave = threadIdx.x >> 6;
    const int l15 = lane & 15, l4 = lane >> 4;

    const int nwg = (int)(gridDim.x * gridDim.y);
    int orig = (int)(blockIdx.y * gridDim.x + blockIdx.x);
    int cpx = nwg >> 3;
    int w = (orig & 7) * cpx + (orig >> 3);
    const int row0 = (w / (int)gridDim.x) * 128;
    const int col0 = (w % (int)gridDim.x) * 128;
    const int wr = wave >> 1, wc = wave & 1;

    f32x4 acc[4][4] = {};

    const int srow = lane >> 2;
    const int scol = (lane & 3) * 8;

    for (int k0 = 0; k0 < K; k0 += 32) {
        __syncthreads();
        #pragma unroll
        for (int it = 0; it < 2; ++it) {
            int chunk = it * 4 + wave;
            const f16* gA = A + (size_t)(row0 + chunk * 16 + srow) * K + k0 + scol;
            gload_lds16(gA, As + chunk * 512);
            const f16* gB = W + (size_t)(col0 + chunk * 16 + srow) * K + k0 + scol;
            gload_lds16(gB, Bs + chunk * 512);
        }
        __syncthreads();

        f16x8 af[4], bf[4];
        #pragma unroll
        for (int m = 0; m < 4; ++m)
            af[m] = *reinterpret_cast<const f16x8*>(As + (wr * 64 + m * 16 + l15) * 32 + l4 * 8);
        #pragma unroll
        for (int n = 0; n < 4; ++n)
            bf[n] = *reinterpret_cast<const f16x8*>(Bs + (wc * 64 + n * 16 + l15) * 32 + l4 * 8);
        #pragma unroll
        for (int m = 0; m < 4; ++m)
            #pragma unroll
            for (int n = 0; n < 4; ++n)
                acc[m][n] = mfma_16x16x32(af[m], bf[n], acc[m][n]);
    }

    if (MODE == 0) {
        f16* qb = (f16*)outp;
        const size_t HS = (size_t)64 * 2048 * 64;
        #pragma unroll
        for (int m = 0; m < 4; ++m) {
            int rbase = row0 + wr * 64 + m * 16 + l4 * 4;
            #pragma unroll
            for (int n = 0; n < 4; ++n) {
                int j = col0 + wc * 64 + n * 16 + l15;
                int which = j >> 10;
                int h = (j >> 6) & 15;
                int d = j & 63;
                float bj = bias[j];
                f16* base = qb + (size_t)which * HS;
                float scale = (which == 0) ? (0.125f * LOG2E) : 1.0f;
                #pragma unroll
                for (int r = 0; r < 4; ++r) {
                    int row = rbase + r;
                    int b = row >> 11, t = row & 2047;
                    size_t off = ((size_t)(b * 16 + h) * 2048 + t) * 64 + d;
                    base[off] = (f16)((acc[m][n][r] + bj) * scale);
                }
            }
        }
    } else {
        float* O = (float*)outp;
        #pragma unroll
        for (int m = 0; m < 4; ++m) {
            int rbase = row0 + wr * 64 + m * 16 + l4 * 4;
            #pragma unroll
            for (int n = 0; n < 4; ++n) {
                int j = col0 + wc * 64 + n * 16 + l15;
                float bj = bias[j];
                #pragma unroll
                for (int r = 0; r < 4; ++r)
                    O[(size_t)(rbase + r) * N + j] = acc[m][n][r] + bj;
            }
        }
    }
}

// ---------------- flash attention: 32x32 MFMA, LDS-P round-trip ----------------
// grid: (bh=64, qblk=16 reversed), block 256 = 4 waves; wave owns 32 q-rows.
// S^T = mfma32(K,Q): lane (hi=lane>>5, q=lane&31) holds S[q][key=crow(r,hi)+32kb],
// crow(r,hi) = (r&3) + 8*(r>>2) + 4*hi. Softmax in-lane; cross-half reduce via
// __shfl_xor(.,32) (verified R1-R5; permlane32_swap(a,a) self-swap is a trap).
__global__ __launch_bounds__(256, 3)
void attn_kernel(const f16* __restrict__ qb, const f16* __restrict__ kb,
                 const f16* __restrict__ vb, f16* __restrict__ ob)
{
    __shared__ __align__(16) f16 Ks[2][4096];     // 16B-chunk col-major: f16 idx = c*512 + key*8
    __shared__ __align__(16) f16 Vs[2][64][68];   // V^T padded: [d][key]
    __shared__ __align__(16) f16 Ps[4][32][68];   // per-wave P: [q][key]

    const int tid = (int)threadIdx.x;
    const int bh = (int)blockIdx.x;
    const int qblk = (int)gridDim.y - 1 - (int)blockIdx.y;   // longest first
    const int lane = tid & 63;
    const int wave = tid >> 6;
    const int l31 = lane & 31;
    const int hi  = lane >> 5;
    const int q0 = qblk * 128;
    const int qw = q0 + wave * 32;

    // Q B-frags (pre-scaled by 0.125*log2e): Q[q=l31][d = ss*16 + hi*8 + j]
    const f16* Qp = qb + ((size_t)bh * 2048 + qw) * 64;
    f16x8 qf[4];
    #pragma unroll
    for (int ss = 0; ss < 4; ++ss)
        qf[ss] = *reinterpret_cast<const f16x8*>(Qp + l31 * 64 + ss * 16 + hi * 8);

    float Mr = -1e30f, Lr = 0.0f;        // softmax state for q = l31
    f32x16 oacc[2] = {};                 // O[q=crow(r,hi)][d = db*32 + l31]

    const int ntiles = 2 * qblk + 2;
    const f16* Kbh = kb + (size_t)bh * 2048 * 64;
    const f16* Vbh = vb + (size_t)bh * 2048 * 64;

    f16x8 vld0, vld1;
    {   // prologue: tile 0
        #pragma unroll
        for (int it = 0; it < 2; ++it) {
            int c = it * 4 + wave;
            gload_lds16(Kbh + lane * 64 + c * 8, &Ks[0][0] + c * 512);
        }
        vld0 = *reinterpret_cast<const f16x8*>(Vbh + lane * 64 + (wave * 2 + 0) * 8);
        vld1 = *reinterpret_cast<const f16x8*>(Vbh + lane * 64 + (wave * 2 + 1) * 8);
    }

    for (int t = 0; t < ntiles; ++t) {
        const int cur = t & 1;
        const int kv0 = t * 64;

        // scatter V_t regs -> Vs[cur] (contiguous 128B per instr, conflict-free)
        #pragma unroll
        for (int it = 0; it < 2; ++it) {
            int dblk = wave * 2 + it;
            const f16x8 v = it ? vld1 : vld0;
            #pragma unroll
            for (int e = 0; e < 8; ++e)
                Vs[cur][dblk * 8 + e][lane] = v[e];
        }

        __syncthreads();   // drains K_t gload_lds; publishes Vs[cur]

        // issue tile t+1 loads into other buffer
        {
            const int kvn = (t + 1 < ntiles) ? (t + 1) * 64 : t * 64;
            const f16* Ktn = Kbh + (size_t)kvn * 64;
            #pragma unroll
            for (int it = 0; it < 2; ++it) {
                int c = it * 4 + wave;
                gload_lds16(Ktn + lane * 64 + c * 8, &Ks[cur ^ 1][0] + c * 512);
            }
            const f16* Vtn = Vbh + (size_t)kvn * 64;
            vld0 = *reinterpret_cast<const f16x8*>(Vtn + lane * 64 + (wave * 2 + 0) * 8);
            vld1 = *reinterpret_cast<const f16x8*>(Vtn + lane * 64 + (wave * 2 + 1) * 8);
        }

        if (kv0 <= qw + 31) {   // wave-uniform compute guard
            const f16* Ksc = &Ks[cur][0];

            // QK^T: S^T[key][q], two 32-key blocks
            f32x16 s0 = {}, s1 = {};
            __builtin_amdgcn_s_setprio(1);
            #pragma unroll
            for (int ss = 0; ss < 4; ++ss) {
                f16x8 kf0 = *reinterpret_cast<const f16x8*>(Ksc + (2 * ss + hi) * 512 + l31 * 8);
                f16x8 kf1 = *reinterpret_cast<const f16x8*>(Ksc + (2 * ss + hi) * 512 + (32 + l31) * 8);
                s0 = mfma_32x32x16(kf0, qf[ss], s0);
                s1 = mfma_32x32x16(kf1, qf[ss], s1);
            }
            __builtin_amdgcn_s_setprio(0);

            if (kv0 + 63 > qw) {   // diagonal: causal mask
                const int qg = qw + l31;
                #pragma unroll
                for (int r = 0; r < 16; ++r) {
                    int k0g = kv0 + (r & 3) + 8 * (r >> 2) + 4 * hi;
                    if (k0g > qg)      s0[r] = -1e30f;
                    if (k0g + 32 > qg) s1[r] = -1e30f;
                }
            }

            // in-lane max over 32, then cross-half via shfl_xor(32) [verified primitive]
            float t16[16];
            #pragma unroll
            for (int i = 0; i < 16; ++i) t16[i] = fmaxf(s0[i], s1[i]);
            #pragma unroll
            for (int st = 8; st > 0; st >>= 1)
                #pragma unroll
                for (int i = 0; i < st; ++i) t16[i] = fmaxf(t16[i], t16[i + st]);
            float mx = t16[0];
            mx = fmaxf(mx, __shfl_xor(mx, 32));

            // defer-max (T13, THR=8 in log2 domain)
            if (__any(mx > Mr + 8.0f)) {
                float nm = fmaxf(Mr, mx);
                float alpha = exp2f(Mr - nm);
                Mr = nm; Lr *= alpha;
                float ar[16];
                #pragma unroll
                for (int r = 0; r < 16; ++r)
                    ar[r] = __shfl(alpha, (r & 3) + 8 * (r >> 2) + 4 * hi);
                #pragma unroll
                for (int r = 0; r < 16; ++r) { oacc[0][r] *= ar[r]; oacc[1][r] *= ar[r]; }
            }

            float e0[16], e1[16];
            #pragma unroll
            for (int r = 0; r < 16; ++r) {
                e0[r] = exp2f(s0[r] - Mr);
                e1[r] = exp2f(s1[r] - Mr);
            }
            float sm[16];
            #pragma unroll
            for (int i = 0; i < 16; ++i) sm[i] = e0[i] + e1[i];
            #pragma unroll
            for (int st = 8; st > 0; st >>= 1)
                #pragma unroll
                for (int i = 0; i < st; ++i) sm[i] += sm[i + st];
            float rs = sm[0];
            rs += __shfl_xor(rs, 32);
            Lr += rs;

            // P -> per-wave LDS, window-grouped: e{b}[4w+u] is key 32b + 8w + 4hi + u
            f16* Pw = &Ps[wave][l31][0];
            #pragma unroll
            for (int w = 0; w < 4; ++w) {
                f16x2 lo0 = cvt_pk_f16(e0[4 * w],     e0[4 * w + 1]);
                f16x2 hi0 = cvt_pk_f16(e0[4 * w + 2], e0[4 * w + 3]);
                f16x4 p4; p4[0] = lo0[0]; p4[1] = lo0[1]; p4[2] = hi0[0]; p4[3] = hi0[1];
                *reinterpret_cast<f16x4*>(Pw + 8 * w + 4 * hi) = p4;
                f16x2 lo1 = cvt_pk_f16(e1[4 * w],     e1[4 * w + 1]);
                f16x2 hi1 = cvt_pk_f16(e1[4 * w + 2], e1[4 * w + 3]);
                f16x4 q4; q4[0] = lo1[0]; q4[1] = lo1[1]; q4[2] = hi1[0]; q4[3] = hi1[1];
                *reinterpret_cast<f16x4*>(Pw + 32 + 8 * w + 4 * hi) = q4;
            }

            // PV: A[row=q=l31][k = 8hi+j] = P[q][key = 16ss + 8hi + j] read from Ps
            __builtin_amdgcn_s_setprio(1);
            #pragma unroll
            for (int ss = 0; ss < 4; ++ss) {
                f16x4 a0 = *reinterpret_cast<const f16x4*>(Pw + 16 * ss + 8 * hi);
                f16x4 a1 = *reinterpret_cast<const f16x4*>(Pw + 16 * ss + 8 * hi + 4);
                f16x8 pa = __builtin_shufflevector(a0, a1, 0, 1, 2, 3, 4, 5, 6, 7);
                #pragma unroll
                for (int db = 0; db < 2; ++db) {
                    const f16* vp = &Vs[cur][db * 32 + l31][16 * ss + 8 * hi];
                    f16x4 v0 = *reinterpret_cast<const f16x4*>(vp);
                    f16x4 v1 = *reinterpret_cast<const f16x4*>(vp + 4);
                    f16x8 vf = __builtin_shufflevector(v0, v1, 0, 1, 2, 3, 4, 5, 6, 7);
                    oacc[db] = mfma_32x32x16(pa, vf, oacc[db]);
                }
            }
            __builtin_amdgcn_s_setprio(0);
        }
    }

    // epilogue: normalize + store O[q][h*64+d] f16
    float rcp = 1.0f / Lr;
    float rr[16];
    #pragma unroll
    for (int r = 0; r < 16; ++r)
        rr[r] = __shfl(rcp, (r & 3) + 8 * (r >> 2) + 4 * hi);

    const int b = bh >> 4, h = bh & 15;
    f16* O = ob + ((size_t)b * 2048 + qw) * 1024 + h * 64;
    #pragma unroll
    for (int db = 0; db < 2; ++db)
        #pragma unroll
        for (int r = 0; r < 16; ++r) {
            int q = (r & 3) + 8 * (r >> 2) + 4 * hi;
            O[(size_t)q * 1024 + db * 32 + l31] = (f16)(oacc[db][r] * rr[r]);
        }
}

extern "C" void kernel_launch(void* const* d_in, const int* in_sizes, int n_in,
                              void* d_out, int out_size, void* d_ws, size_t ws_size,
                              hipStream_t stream)
{
    const float* x    = (const float*)d_in[0];
    const float* qkvw = (const float*)d_in[1];
    const float* qkvb = (const float*)d_in[2];
    const float* outw = (const float*)d_in[3];
    const float* outb = (const float*)d_in[4];
    float* out = (float*)d_out;

    f16* x_h    = (f16*)d_ws;
    f16* qkvw_h = x_h + (size_t)8192 * 1024;
    f16* outw_h = qkvw_h + (size_t)3072 * 1024;
    f16* q_buf  = outw_h + (size_t)1024 * 1024;
    f16* att_o  = q_buf + (size_t)3 * 8388608;

    cast_f32_f16<<<8192, 256, 0, stream>>>(x, x_h, 2097152);
    cast_f32_f16<<<3072, 256, 0, stream>>>(qkvw, qkvw_h, 786432);
    cast_f32_f16<<<1024, 256, 0, stream>>>(outw, outw_h, 262144);

    gemm_tn<0><<<dim3(24, 64), 256, 0, stream>>>(x_h, qkvw_h, qkvb, q_buf, 8192, 3072, 1024);
    attn_kernel<<<dim3(64, 16), 256, 0, stream>>>(q_buf, q_buf + 8388608, q_buf + 2 * 8388608, att_o);
    gemm_tn<1><<<dim3(8, 64), 256, 0, stream>>>(att_o, outw_h, outb, out, 8192, 1024, 1024);
}